// Round 13
// baseline (139.371 us; speedup 1.0000x reference)
//
#include <hip/hip_runtime.h>

// CIN_51539607712 — R15: 2-h merged iterations. Calibration across R4/R13/R14
// shows per-iteration const ~1050 cy INVARIANT to MFMA/ds_read/stage counts —
// it's the wait-pair + exposed latency per iteration. So halve the number of
// iterations: each K-loop iter processes TWO h-steps (stage 2 images = 4 DMA,
// 4 ds_read_b128, 8 xl loads, 16 MFMA + 16 acc-fma, ONE wait-pair).
// Iters: 64->32 (big), 16->8 (L0). LDS slots = 1024 u32 (2 images) x 2 slots
// = the existing 2048-u32 wave region; epilogue unchanged.
// vmem ledger: group(i) = [stage(4), xl(8)] = 12 ops issued during iter i-2;
// top of iter i: vmcnt(12) drains group i, leaves group i+1 in flight.
// Peeled last iter: vmcnt(0). 0x0F7C = vmcnt(12).
// Numerics = R14 (1-MFMA RNE split, absmax 0.125, threshold 0.4525).
// Geometry = R4 champion: grid 256, 512 thr, 8 waves (kh = w&1, nq = w>>1),
// 64-row blocks, barrier-free counted-vmcnt K-loop, fused prep.
// out[r,n] = sum_h xl[r,h] * Y_h[r,n],  Y_h[r,n] = sum_m x0[r,m] W[h*32+m,n].

typedef unsigned int u32;
typedef __attribute__((ext_vector_type(8))) short short8;
typedef __attribute__((ext_vector_type(4))) float f32x4;
typedef __attribute__((ext_vector_type(4))) u32 u32x4;

#define R_TOTAL 16384
#define GLOBAL_AS __attribute__((address_space(1)))
#define LDS_AS __attribute__((address_space(3)))

union PackU { u32 u[4]; short8 s; };
union PackB { u32x4 v; short8 s; };

// pack with round-to-nearest-even (both x0 fragments and W prep)
__device__ __forceinline__ u32 pack_rne(float a, float b) {
  u32 r;
  asm("v_cvt_pk_bf16_f32 %0, %1, %2" : "=v"(r) : "v"(a), "v"(b));
  return r;
}

// ---------------- fused prep kernel ----------------
// blocks 0..127: build X0T[m][b*16+d] = in[b][m][d]  (32 x 16384)
// blocks 128..255 / 256..767 / 768..1279: swizzle W0 / W1 / W2.
__device__ __forceinline__ void build_x0t_body(const float* __restrict__ in,
                                               float* __restrict__ x0t,
                                               int bid, int tid, float* t) {
  const int b0 = bid * 8;
  #pragma unroll
  for (int rep = 0; rep < 4; ++rep) {
    int idx = tid + rep * 256;
    *(float4*)&t[idx * 4] = *(const float4*)&in[(size_t)b0 * 512 + idx * 4];
  }
  __syncthreads();
  #pragma unroll
  for (int rep = 0; rep < 4; ++rep) {
    int idx = tid + rep * 256;     // 0..1023: m(32) x bl(8) x dq(4)
    int m = idx >> 5, rem = idx & 31;
    int bl = rem >> 2, dq = rem & 3;
    *(float4*)&x0t[(size_t)m * R_TOTAL + (b0 + bl) * 16 + dq * 4] =
        *(const float4*)&t[bl * 512 + m * 16 + dq * 4];
  }
}

// Block (t = bid>>2, nq = bid&3). 2 KB image: [nl 0..31][p 0..3] 16B blocks;
// position p holds logical block q = p ^ (nl&3); block q = RNE-packed
// W[t*32+q*8+j][nq*32+nl], j pairs packed (even=lo half, odd=hi half).
__device__ __forceinline__ void swizzle_body(const float* __restrict__ W,
                                             u32* __restrict__ wt,
                                             int bid, int tid, float* wl) {
  const int t = bid >> 2, nq = bid & 3;
  {
    int kk = tid >> 3, c4 = tid & 7;
    float4 v = *(const float4*)&W[(size_t)(t * 32 + kk) * 128 + nq * 32 + c4 * 4];
    wl[kk * 33 + c4 * 4 + 0] = v.x;
    wl[kk * 33 + c4 * 4 + 1] = v.y;
    wl[kk * 33 + c4 * 4 + 2] = v.z;
    wl[kk * 33 + c4 * 4 + 3] = v.w;
  }
  __syncthreads();
  if (tid < 128) {
    int nl = tid >> 2, p = tid & 3;
    int q = p ^ (nl & 3);
    u32 o[4];
    #pragma unroll
    for (int jj = 0; jj < 4; ++jj)
      o[jj] = pack_rne(wl[(q * 8 + 2 * jj + 0) * 33 + nl],
                       wl[(q * 8 + 2 * jj + 1) * 33 + nl]);
    *(u32x4*)(wt + (size_t)(t * 4 + nq) * 512 + nl * 16 + p * 4) =
        u32x4{o[0], o[1], o[2], o[3]};
  }
}

__global__ __launch_bounds__(256) void prep_all(
    const float* __restrict__ in, float* __restrict__ x0t,
    const float* __restrict__ W0, u32* __restrict__ wt0,
    const float* __restrict__ W1, u32* __restrict__ wt1,
    const float* __restrict__ W2, u32* __restrict__ wt2) {
  __shared__ float sh[4096];
  const int b = blockIdx.x, tid = threadIdx.x;
  if (b < 128)      build_x0t_body(in, x0t, b, tid, sh);
  else if (b < 256) swizzle_body(W0, wt0, b - 128, tid, sh);
  else if (b < 768) swizzle_body(W1, wt1, b - 256, tid, sh);
  else              swizzle_body(W2, wt2, b - 768, tid, sh);
}

// ---------------- per-wave staging: one 2 KB image via global_load_lds -------
__device__ __forceinline__ void stage2k(const u32* g, u32* l, int lane) {
  const GLOBAL_AS u32* gp = (const GLOBAL_AS u32*)g;
  LDS_AS u32* lp = (LDS_AS u32*)l;
  #pragma unroll
  for (int i = 0; i < 2; ++i)
    __builtin_amdgcn_global_load_lds(gp + i * 256 + lane * 4, lp + i * 256, 16, 0, 0);
}

// Merged K-loop iteration I covers h-tiles (t0+2I, t0+2I+1), slot SLOT = I&1
// (1024 u32: image0 at +0, image1 at +512). WAITIMM: 0x0F7C = vmcnt(12)
// (group I drained, group I+1's 12 ops in flight), 0x0F70 = vmcnt(0) (last).
// Group issue order: [stage2k x2 (4 ops), xl x8] for iter I+2.
#define KITER(I, SLOT, WAITIMM, DO_STAGE)                                      \
  {                                                                            \
    __builtin_amdgcn_s_waitcnt(WAITIMM);                                       \
    __builtin_amdgcn_sched_barrier(0);                                         \
    f32x4 xlc[8];                                                              \
    _Pragma("unroll")                                                          \
    for (int z = 0; z < 8; ++z) xlc[z] = xn[SLOT][z];                          \
    const u32* buf = mybuf + (SLOT) * 1024;                                    \
    PackB b00, b01, b10, b11;                                                  \
    {                                                                          \
      const u32* i0r0 = buf + ln15 * 16;                                       \
      const u32* i0r1 = buf + (16 + ln15) * 16;                                \
      b00.v = *(const u32x4*)(i0r0 + ((q ^ sw) * 4));                          \
      b01.v = *(const u32x4*)(i0r1 + ((q ^ sw) * 4));                          \
      const u32* i1r0 = buf + 512 + ln15 * 16;                                 \
      const u32* i1r1 = buf + 512 + (16 + ln15) * 16;                          \
      b10.v = *(const u32x4*)(i1r0 + ((q ^ sw) * 4));                          \
      b11.v = *(const u32x4*)(i1r1 + ((q ^ sw) * 4));                          \
    }                                                                          \
    asm volatile("s_waitcnt lgkmcnt(0)" ::: "memory");                         \
    __builtin_amdgcn_sched_barrier(0);                                         \
    if (DO_STAGE) {                                                            \
      const int tb = t0 + 2 * (I) + 4;                                         \
      stage2k(wt + (size_t)(tb * 4 + nq) * 512, mybuf + (SLOT) * 1024, lane);  \
      stage2k(wt + (size_t)((tb + 1) * 4 + nq) * 512,                          \
              mybuf + (SLOT) * 1024 + 512, lane);                              \
      __builtin_amdgcn_sched_barrier(0);                                       \
      const float* xp0 = xt + (size_t)tb * R_TOTAL + r0;                       \
      const float* xp1 = xt + (size_t)(tb + 1) * R_TOTAL + r0;                 \
      xn[SLOT][0] = *(const f32x4*)(xp0 + 0 + q * 4);                          \
      xn[SLOT][1] = *(const f32x4*)(xp0 + 16 + q * 4);                         \
      xn[SLOT][2] = *(const f32x4*)(xp0 + 32 + q * 4);                         \
      xn[SLOT][3] = *(const f32x4*)(xp0 + 48 + q * 4);                         \
      xn[SLOT][4] = *(const f32x4*)(xp1 + 0 + q * 4);                          \
      xn[SLOT][5] = *(const f32x4*)(xp1 + 16 + q * 4);                         \
      xn[SLOT][6] = *(const f32x4*)(xp1 + 32 + q * 4);                         \
      xn[SLOT][7] = *(const f32x4*)(xp1 + 48 + q * 4);                         \
    }                                                                          \
    __builtin_amdgcn_sched_barrier(0);                                         \
    __builtin_amdgcn_s_setprio(1);                                             \
    _Pragma("unroll")                                                          \
    for (int f = 0; f < 4; ++f) {                                              \
      f32x4 Y = __builtin_amdgcn_mfma_f32_16x16x32_bf16(Ah[f].s, b00.s, zero4, 0, 0, 0); \
      acc[f][0] += xlc[f] * Y;                                                 \
    }                                                                          \
    _Pragma("unroll")                                                          \
    for (int f = 0; f < 4; ++f) {                                              \
      f32x4 Y = __builtin_amdgcn_mfma_f32_16x16x32_bf16(Ah[f].s, b01.s, zero4, 0, 0, 0); \
      acc[f][1] += xlc[f] * Y;                                                 \
    }                                                                          \
    _Pragma("unroll")                                                          \
    for (int f = 0; f < 4; ++f) {                                              \
      f32x4 Y = __builtin_amdgcn_mfma_f32_16x16x32_bf16(Ah[f].s, b10.s, zero4, 0, 0, 0); \
      acc[f][0] += xlc[4 + f] * Y;                                             \
    }                                                                          \
    _Pragma("unroll")                                                          \
    for (int f = 0; f < 4; ++f) {                                              \
      f32x4 Y = __builtin_amdgcn_mfma_f32_16x16x32_bf16(Ah[f].s, b11.s, zero4, 0, 0, 0); \
      acc[f][1] += xlc[4 + f] * Y;                                             \
    }                                                                          \
    __builtin_amdgcn_s_setprio(0);                                             \
    __builtin_amdgcn_sched_barrier(0);                                         \
  }

// ---------------- main layer kernel ----------------
template <int NT, bool RELU, bool STORE_X>
__global__ __launch_bounds__(512, 2) void layer_mfma(
    const float* __restrict__ xt,    // NT x R (transposed prev activation)
    const float* __restrict__ x0t,   // 32 x R
    const u32* __restrict__ wt,      // NT*4 quarter images (512 u32 each)
    const float* __restrict__ bias,  // 128
    float* __restrict__ xoutT,       // 128 x R (if STORE_X)
    float* __restrict__ osum)        // d_out + layer offset, stride 384
{
  constexpr int HT = NT / 2;         // h-tiles per wave
  constexpr int M = HT / 2;          // merged iterations
  static_assert((M & 1) == 0 && M >= 4, "merged pair-loop needs even M >= 4");
  __shared__ u32 smem[16384];        // 64 KB: 8 waves x 2048 u32
                                     // (K-loop: 2 slots x 1024 u32 = 2 image-pairs)

  const int tid = threadIdx.x;
  const int w = tid >> 6, lane = tid & 63;
  const int ln15 = lane & 15, q = lane >> 4;
  const int kh = w & 1, nq = w >> 1;
  const int r0 = blockIdx.x * 64;
  const int sw = ln15 & 3;           // 4-position XOR swizzle (2 KB image)
  u32* mybuf = smem + w * 2048;

  // ---- loop-invariant A fragments: RNE-rounded x0 rows (A[i=ln15][k=q*8+j])
  PackU Ah[4];
  #pragma unroll
  for (int f = 0; f < 4; ++f) {
    const int rbase = r0 + f * 16 + ln15;
    float e[8];
    #pragma unroll
    for (int j = 0; j < 8; ++j) e[j] = x0t[(size_t)(q * 8 + j) * R_TOTAL + rbase];
    #pragma unroll
    for (int jj = 0; jj < 4; ++jj)
      Ah[f].u[jj] = pack_rne(e[2 * jj], e[2 * jj + 1]);
  }

  f32x4 acc[4][2];
  #pragma unroll
  for (int f = 0; f < 4; ++f)
    #pragma unroll
    for (int c = 0; c < 2; ++c) acc[f][c] = f32x4{0.f, 0.f, 0.f, 0.f};
  const f32x4 zero4 = {0.f, 0.f, 0.f, 0.f};

  const int t0 = kh * HT;

  // ---- prologue: 2-deep prefetch of merged groups 0 and 1 ----
  f32x4 xn[2][8];
  #pragma unroll
  for (int g = 0; g < 2; ++g) {
    const int tb = t0 + 2 * g;
    stage2k(wt + (size_t)(tb * 4 + nq) * 512, mybuf + g * 1024, lane);
    stage2k(wt + (size_t)((tb + 1) * 4 + nq) * 512, mybuf + g * 1024 + 512, lane);
    __builtin_amdgcn_sched_barrier(0);
    const float* xp0 = xt + (size_t)tb * R_TOTAL + r0;
    const float* xp1 = xt + (size_t)(tb + 1) * R_TOTAL + r0;
    xn[g][0] = *(const f32x4*)(xp0 + 0 + q * 4);
    xn[g][1] = *(const f32x4*)(xp0 + 16 + q * 4);
    xn[g][2] = *(const f32x4*)(xp0 + 32 + q * 4);
    xn[g][3] = *(const f32x4*)(xp0 + 48 + q * 4);
    xn[g][4] = *(const f32x4*)(xp1 + 0 + q * 4);
    xn[g][5] = *(const f32x4*)(xp1 + 16 + q * 4);
    xn[g][6] = *(const f32x4*)(xp1 + 32 + q * 4);
    xn[g][7] = *(const f32x4*)(xp1 + 48 + q * 4);
    __builtin_amdgcn_sched_barrier(0);
  }

  // ---- steady state: iter i stages group i+2, waits vmcnt(12) ----
  for (int i = 0; i < M - 2; i += 2) {
    KITER(i, 0, 0x0F7C, 1);
    KITER(i + 1, 1, 0x0F7C, 1);
  }
  // ---- peeled last pair: no staging; final iter drains to vmcnt(0) ----
  KITER(M - 2, 0, 0x0F7C, 0);
  KITER(M - 1, 1, 0x0F70, 0);

  // ---------------- epilogue ----------------
  __syncthreads();                  // K-loop LDS regions now reusable
  if (kh == 1) {                    // dump partial acc into own region (8 KB)
    u32* reg = mybuf;
    #pragma unroll
    for (int f = 0; f < 4; ++f)
      #pragma unroll
      for (int c = 0; c < 2; ++c)
        *(f32x4*)(reg + ((size_t)(f * 2 + c) * 64 + lane) * 4) = acc[f][c];
  }
  __syncthreads();
  if (kh == 0) {
    const u32* reg = smem + (w + 1) * 2048;   // partner (kh=1, same nq)
    float bs[2];
    #pragma unroll
    for (int c = 0; c < 2; ++c) bs[c] = bias[nq * 32 + c * 16 + ln15];

    f32x4 vv[4][2];
    #pragma unroll
    for (int f = 0; f < 4; ++f) {
      #pragma unroll
      for (int c = 0; c < 2; ++c) {
        f32x4 part = *(const f32x4*)(reg + ((size_t)(f * 2 + c) * 64 + lane) * 4);
        f32x4 v = acc[f][c] + part;
        v.x += bs[c]; v.y += bs[c]; v.z += bs[c]; v.w += bs[c];
        if (RELU) {
          v.x = fmaxf(v.x, 0.f); v.y = fmaxf(v.y, 0.f);
          v.z = fmaxf(v.z, 0.f); v.w = fmaxf(v.w, 0.f);
        }
        vv[f][c] = v;
        float s = v.x + v.y + v.z + v.w;       // 4 rows of batch (r0>>4)+f
        s += __shfl_xor(s, 16, 64);
        s += __shfl_xor(s, 32, 64);
        if (q == 0)
          osum[(size_t)((r0 >> 4) + f) * 384 + nq * 32 + c * 16 + ln15] = s;
      }
    }

    if (STORE_X) {
      // transpose via own LDS region, then 64B-contiguous stores to XT.
      u32* myreg = mybuf;
      #pragma unroll
      for (int f = 0; f < 4; ++f)
        #pragma unroll
        for (int c = 0; c < 2; ++c)
          *(f32x4*)(myreg + ((size_t)(f * 2 + c) * 64 + lane) * 4) = vv[f][c];
      // element (r_local, lcol): frag (f=r>>4, c=lcol>>4), lane q=(r>>2)&3,
      // ln15=lcol&15, comp rr=r&3. Round (c,s): lane -> col=c*16+(lane>>2),
      // r_local = s*16 + (lane&3)*4.
      #pragma unroll
      for (int c = 0; c < 2; ++c) {
        #pragma unroll
        for (int s = 0; s < 4; ++s) {
          f32x4 vr = *(const f32x4*)(myreg +
              ((size_t)(s * 2 + c) * 64 + (lane & 3) * 16 + (lane >> 2)) * 4);
          const int col = nq * 32 + c * 16 + (lane >> 2);
          *(f32x4*)&xoutT[(size_t)col * R_TOTAL + r0 + s * 16 + (lane & 3) * 4] = vr;
        }
      }
    }
  }
}

extern "C" void kernel_launch(void* const* d_in, const int* in_sizes, int n_in,
                              void* d_out, int out_size, void* d_ws, size_t ws_size,
                              hipStream_t stream) {
  const float* in = (const float*)d_in[0];
  const float* W0 = (const float*)d_in[1];
  const float* b0 = (const float*)d_in[2];
  const float* W1 = (const float*)d_in[3];
  const float* b1 = (const float*)d_in[4];
  const float* W2 = (const float*)d_in[5];
  const float* b2 = (const float*)d_in[6];
  float* out = (float*)d_out;

  float* X0T = (float*)d_ws;                         // 32 x 16384   (2 MB)
  float* X1T = X0T + (size_t)32 * R_TOTAL;           // 128 x 16384  (8 MB)
  float* X2T = X1T + (size_t)128 * R_TOTAL;          // 128 x 16384  (8 MB)
  u32* Wt0 = (u32*)(X2T + (size_t)128 * R_TOTAL);    // 32*4*512 u32   (256 KB)
  u32* Wt1 = Wt0 + (size_t)32 * 4 * 512;             // 128*4*512 u32  (1 MB)
  u32* Wt2 = Wt1 + (size_t)128 * 4 * 512;            // 128*4*512 u32  (1 MB)
  // total ws: ~20.3 MB

  prep_all<<<1280, 256, 0, stream>>>(in, X0T, W0, Wt0, W1, Wt1, W2, Wt2);

  layer_mfma<32, true, true><<<256, 512, 0, stream>>>(X0T, X0T, Wt0, b0, X1T, out + 0);
  layer_mfma<128, true, true><<<256, 512, 0, stream>>>(X1T, X0T, Wt1, b1, X2T, out + 128);
  layer_mfma<128, false, false><<<256, 512, 0, stream>>>(X2T, X0T, Wt2, b2, nullptr, out + 256);
}

// Round 14
// 137.153 us; speedup vs baseline: 1.0162x; 1.0162x over previous
//
#include <hip/hip_runtime.h>

// CIN_51539607712 — R16: R14 base (best: 137.7 us) + const-cuts.
// Model (calibrated R13/R14/R15): period = ~1050cy const + serial MFMA;
// R15 proved const is NOT wait-count. Attacking its components:
// (1) B-reg double-buffer: ds_read slot I+1 during iter I, counted
//     lgkmcnt(2) — removes ~110cy/wave/h exposed LDS latency. Ledger =
//     R7's verified vmcnt(4)-split: groups [D(2), xl(4)]; top-of-iter
//     vmcnt(4) drains xl(I) + D(I+1) (slot I+1 readable, xl(I) usable).
// (2) xlc copies killed: MFMA+fma consume xn[SLOT] BEFORE the xl(I+2)
//     loads overwrite it (issue order [D..., MFMA+fma, xl] keeps the
//     6-op group shape: D before xl).
// (3) Fewer sched_barriers: fences only at ledger boundaries; ds-issue/
//     MFMA/fma form one region the compiler may interleave (m141 lesson).
// Numerics = R14 (1-MFMA RNE, absmax 0.125 vs thr 0.4525). Geometry = R4
// champion: grid 256, 512 thr, 8 waves (kh=w&1, nq=w>>1), 64-row blocks.
// out[r,n] = sum_h xl[r,h] * Y_h[r,n],  Y_h[r,n] = sum_m x0[r,m] W[h*32+m,n].

typedef unsigned int u32;
typedef __attribute__((ext_vector_type(8))) short short8;
typedef __attribute__((ext_vector_type(4))) float f32x4;
typedef __attribute__((ext_vector_type(4))) u32 u32x4;

#define R_TOTAL 16384
#define GLOBAL_AS __attribute__((address_space(1)))
#define LDS_AS __attribute__((address_space(3)))

union PackU { u32 u[4]; short8 s; };
union PackB { u32x4 v; short8 s; };

// pack with round-to-nearest-even (both x0 fragments and W prep)
__device__ __forceinline__ u32 pack_rne(float a, float b) {
  u32 r;
  asm("v_cvt_pk_bf16_f32 %0, %1, %2" : "=v"(r) : "v"(a), "v"(b));
  return r;
}

// ---------------- fused prep kernel ----------------
// blocks 0..127: build X0T[m][b*16+d] = in[b][m][d]  (32 x 16384)
// blocks 128..255 / 256..767 / 768..1279: swizzle W0 / W1 / W2.
__device__ __forceinline__ void build_x0t_body(const float* __restrict__ in,
                                               float* __restrict__ x0t,
                                               int bid, int tid, float* t) {
  const int b0 = bid * 8;
  #pragma unroll
  for (int rep = 0; rep < 4; ++rep) {
    int idx = tid + rep * 256;
    *(float4*)&t[idx * 4] = *(const float4*)&in[(size_t)b0 * 512 + idx * 4];
  }
  __syncthreads();
  #pragma unroll
  for (int rep = 0; rep < 4; ++rep) {
    int idx = tid + rep * 256;     // 0..1023: m(32) x bl(8) x dq(4)
    int m = idx >> 5, rem = idx & 31;
    int bl = rem >> 2, dq = rem & 3;
    *(float4*)&x0t[(size_t)m * R_TOTAL + (b0 + bl) * 16 + dq * 4] =
        *(const float4*)&t[bl * 512 + m * 16 + dq * 4];
  }
}

// Block (t = bid>>2, nq = bid&3). 2 KB image: [nl 0..31][p 0..3] 16B blocks;
// position p holds logical block q = p ^ (nl&3); block q = RNE-packed
// W[t*32+q*8+j][nq*32+nl], j pairs packed (even=lo half, odd=hi half).
__device__ __forceinline__ void swizzle_body(const float* __restrict__ W,
                                             u32* __restrict__ wt,
                                             int bid, int tid, float* wl) {
  const int t = bid >> 2, nq = bid & 3;
  {
    int kk = tid >> 3, c4 = tid & 7;
    float4 v = *(const float4*)&W[(size_t)(t * 32 + kk) * 128 + nq * 32 + c4 * 4];
    wl[kk * 33 + c4 * 4 + 0] = v.x;
    wl[kk * 33 + c4 * 4 + 1] = v.y;
    wl[kk * 33 + c4 * 4 + 2] = v.z;
    wl[kk * 33 + c4 * 4 + 3] = v.w;
  }
  __syncthreads();
  if (tid < 128) {
    int nl = tid >> 2, p = tid & 3;
    int q = p ^ (nl & 3);
    u32 o[4];
    #pragma unroll
    for (int jj = 0; jj < 4; ++jj)
      o[jj] = pack_rne(wl[(q * 8 + 2 * jj + 0) * 33 + nl],
                       wl[(q * 8 + 2 * jj + 1) * 33 + nl]);
    *(u32x4*)(wt + (size_t)(t * 4 + nq) * 512 + nl * 16 + p * 4) =
        u32x4{o[0], o[1], o[2], o[3]};
  }
}

__global__ __launch_bounds__(256) void prep_all(
    const float* __restrict__ in, float* __restrict__ x0t,
    const float* __restrict__ W0, u32* __restrict__ wt0,
    const float* __restrict__ W1, u32* __restrict__ wt1,
    const float* __restrict__ W2, u32* __restrict__ wt2) {
  __shared__ float sh[4096];
  const int b = blockIdx.x, tid = threadIdx.x;
  if (b < 128)      build_x0t_body(in, x0t, b, tid, sh);
  else if (b < 256) swizzle_body(W0, wt0, b - 128, tid, sh);
  else if (b < 768) swizzle_body(W1, wt1, b - 256, tid, sh);
  else              swizzle_body(W2, wt2, b - 768, tid, sh);
}

// ---------------- per-wave staging: one 2 KB image via global_load_lds -------
__device__ __forceinline__ void stage2k(const u32* g, u32* l, int lane) {
  const GLOBAL_AS u32* gp = (const GLOBAL_AS u32*)g;
  LDS_AS u32* lp = (LDS_AS u32*)l;
  #pragma unroll
  for (int i = 0; i < 2; ++i)
    __builtin_amdgcn_global_load_lds(gp + i * 256 + lane * 4, lp + i * 256, 16, 0, 0);
}

// s_waitcnt imm (gfx9): vm[3:0]=b3:0, exp=b6:4, lgkm=b11:8, vm[5:4]=b15:14.
// 0x0F74 = vmcnt(4)   0x0F70 = vmcnt(0)   0x0F7A = vmcnt(10)
// 0xC27F = lgkmcnt(2) 0xC07F = lgkmcnt(0)
#define SB() __builtin_amdgcn_sched_barrier(0)

// KITER(I): h-tile t0+I, SLOT = I&1. BCUR = fragments of slot I (read last
// iter); BNXT = fragments of slot I+1 (read now, waited next iter).
// vmem group(I+2) = [D(2) after lgkm-wait, xl(4) after fma] — D before xl.
#define KITER(I, SLOT, TOPVM, LGKM, DO_STAGE, READ_NEXT, BCUR, BNXT)           \
  {                                                                            \
    __builtin_amdgcn_s_waitcnt(TOPVM);                                         \
    SB();                                                                      \
    if (READ_NEXT) {                                                           \
      const u32* nbuf = mybuf + ((SLOT) ^ 1) * 512;                            \
      BNXT[0].v = *(const u32x4*)(nbuf + ln15 * 16 + ((q ^ sw) * 4));          \
      BNXT[1].v = *(const u32x4*)(nbuf + (16 + ln15) * 16 + ((q ^ sw) * 4));   \
    }                                                                          \
    SB();                                                                      \
    __builtin_amdgcn_s_waitcnt(LGKM);                                          \
    SB();                                                                      \
    if (DO_STAGE) {                                                            \
      stage2k(wt + (size_t)((t0 + (I) + 2) * 4 + nq) * 512,                    \
              mybuf + (SLOT) * 512, lane);                                     \
    }                                                                          \
    SB();                                                                      \
    __builtin_amdgcn_s_setprio(1);                                             \
    f32x4 Y0[4], Y1[4];                                                        \
    _Pragma("unroll")                                                          \
    for (int f = 0; f < 4; ++f)                                                \
      Y0[f] = __builtin_amdgcn_mfma_f32_16x16x32_bf16(Ah[f].s, BCUR[0].s, zero4, 0, 0, 0); \
    _Pragma("unroll")                                                          \
    for (int f = 0; f < 4; ++f)                                                \
      Y1[f] = __builtin_amdgcn_mfma_f32_16x16x32_bf16(Ah[f].s, BCUR[1].s, zero4, 0, 0, 0); \
    _Pragma("unroll")                                                          \
    for (int f = 0; f < 4; ++f) {                                              \
      acc[f][0] += xn[SLOT][f] * Y0[f];                                        \
      acc[f][1] += xn[SLOT][f] * Y1[f];                                        \
    }                                                                          \
    __builtin_amdgcn_s_setprio(0);                                             \
    SB();                                                                      \
    if (DO_STAGE) {                                                            \
      const float* xp = xt + (size_t)(t0 + (I) + 2) * R_TOTAL + r0;            \
      xn[SLOT][0] = *(const f32x4*)(xp + 0 + q * 4);                           \
      xn[SLOT][1] = *(const f32x4*)(xp + 16 + q * 4);                          \
      xn[SLOT][2] = *(const f32x4*)(xp + 32 + q * 4);                          \
      xn[SLOT][3] = *(const f32x4*)(xp + 48 + q * 4);                          \
    }                                                                          \
    SB();                                                                      \
  }

// ---------------- main layer kernel ----------------
template <int NT, bool RELU, bool STORE_X>
__global__ __launch_bounds__(512, 2) void layer_mfma(
    const float* __restrict__ xt,    // NT x R (transposed prev activation)
    const float* __restrict__ x0t,   // 32 x R
    const u32* __restrict__ wt,      // NT*4 quarter images (512 u32 each)
    const float* __restrict__ bias,  // 128
    float* __restrict__ xoutT,       // 128 x R (if STORE_X)
    float* __restrict__ osum)        // d_out + layer offset, stride 384
{
  constexpr int HT = NT / 2;
  static_assert((HT & 1) == 0 && HT >= 4, "pair-loop needs even HT >= 4");
  __shared__ u32 smem[16384];        // 64 KB: 8 waves x 2048 u32
                                     // (K-loop uses first 1024: 2 x 512 slots)

  const int tid = threadIdx.x;
  const int w = tid >> 6, lane = tid & 63;
  const int ln15 = lane & 15, q = lane >> 4;
  const int kh = w & 1, nq = w >> 1;
  const int r0 = blockIdx.x * 64;
  const int sw = ln15 & 3;           // 4-position XOR swizzle (2 KB image)
  u32* mybuf = smem + w * 2048;

  // ---- loop-invariant A fragments: RNE-rounded x0 rows (A[i=ln15][k=q*8+j])
  PackU Ah[4];
  #pragma unroll
  for (int f = 0; f < 4; ++f) {
    const int rbase = r0 + f * 16 + ln15;
    float e[8];
    #pragma unroll
    for (int j = 0; j < 8; ++j) e[j] = x0t[(size_t)(q * 8 + j) * R_TOTAL + rbase];
    #pragma unroll
    for (int jj = 0; jj < 4; ++jj)
      Ah[f].u[jj] = pack_rne(e[2 * jj], e[2 * jj + 1]);
  }

  f32x4 acc[4][2];
  #pragma unroll
  for (int f = 0; f < 4; ++f)
    #pragma unroll
    for (int c = 0; c < 2; ++c) acc[f][c] = f32x4{0.f, 0.f, 0.f, 0.f};
  const f32x4 zero4 = {0.f, 0.f, 0.f, 0.f};

  const int t0 = kh * HT;

  // ---- prologue: issue [D(0), xl(0), D(1), xl(1)] in order, then expose
  // slot 0 (vmcnt(10) drains D(0)) and prime BCUR = ba.
  f32x4 xn[2][4];
  stage2k(wt + (size_t)(t0 * 4 + nq) * 512, mybuf, lane);
  SB();
  {
    const float* xp = xt + (size_t)t0 * R_TOTAL + r0;
    xn[0][0] = *(const f32x4*)(xp + 0 + q * 4);
    xn[0][1] = *(const f32x4*)(xp + 16 + q * 4);
    xn[0][2] = *(const f32x4*)(xp + 32 + q * 4);
    xn[0][3] = *(const f32x4*)(xp + 48 + q * 4);
  }
  SB();
  stage2k(wt + (size_t)((t0 + 1) * 4 + nq) * 512, mybuf + 512, lane);
  SB();
  {
    const float* xp = xt + (size_t)(t0 + 1) * R_TOTAL + r0;
    xn[1][0] = *(const f32x4*)(xp + 0 + q * 4);
    xn[1][1] = *(const f32x4*)(xp + 16 + q * 4);
    xn[1][2] = *(const f32x4*)(xp + 32 + q * 4);
    xn[1][3] = *(const f32x4*)(xp + 48 + q * 4);
  }
  SB();
  __builtin_amdgcn_s_waitcnt(0x0F7A);  // vmcnt(10): D(0) done, slot 0 valid
  SB();
  PackB ba[2], bb[2];
  {
    ba[0].v = *(const u32x4*)(mybuf + ln15 * 16 + ((q ^ sw) * 4));
    ba[1].v = *(const u32x4*)(mybuf + (16 + ln15) * 16 + ((q ^ sw) * 4));
  }
  SB();

  // ---- steady state: vmcnt(4) top-wait, lgkmcnt(2) before MFMA ----
  for (int i = 0; i < HT - 2; i += 2) {
    KITER(i,     0, 0x0F74, 0xC27F, 1, 1, ba, bb);
    KITER(i + 1, 1, 0x0F74, 0xC27F, 1, 1, bb, ba);
  }
  // ---- peeled last pair: no staging; final iter drains both counters ----
  KITER(HT - 2, 0, 0x0F74, 0xC27F, 0, 1, ba, bb);
  KITER(HT - 1, 1, 0x0F70, 0xC07F, 0, 0, bb, ba);

  // ---------------- epilogue ----------------
  __syncthreads();                  // K-loop LDS regions now reusable
  if (kh == 1) {                    // dump partial acc into own region (8 KB)
    u32* reg = mybuf;
    #pragma unroll
    for (int f = 0; f < 4; ++f)
      #pragma unroll
      for (int c = 0; c < 2; ++c)
        *(f32x4*)(reg + ((size_t)(f * 2 + c) * 64 + lane) * 4) = acc[f][c];
  }
  __syncthreads();
  if (kh == 0) {
    const u32* reg = smem + (w + 1) * 2048;   // partner (kh=1, same nq)
    float bs[2];
    #pragma unroll
    for (int c = 0; c < 2; ++c) bs[c] = bias[nq * 32 + c * 16 + ln15];

    f32x4 vv[4][2];
    #pragma unroll
    for (int f = 0; f < 4; ++f) {
      #pragma unroll
      for (int c = 0; c < 2; ++c) {
        f32x4 part = *(const f32x4*)(reg + ((size_t)(f * 2 + c) * 64 + lane) * 4);
        f32x4 v = acc[f][c] + part;
        v.x += bs[c]; v.y += bs[c]; v.z += bs[c]; v.w += bs[c];
        if (RELU) {
          v.x = fmaxf(v.x, 0.f); v.y = fmaxf(v.y, 0.f);
          v.z = fmaxf(v.z, 0.f); v.w = fmaxf(v.w, 0.f);
        }
        vv[f][c] = v;
        float s = v.x + v.y + v.z + v.w;       // 4 rows of batch (r0>>4)+f
        s += __shfl_xor(s, 16, 64);
        s += __shfl_xor(s, 32, 64);
        if (q == 0)
          osum[(size_t)((r0 >> 4) + f) * 384 + nq * 32 + c * 16 + ln15] = s;
      }
    }

    if (STORE_X) {
      // transpose via own LDS region, then 64B-contiguous stores to XT.
      u32* myreg = mybuf;
      #pragma unroll
      for (int f = 0; f < 4; ++f)
        #pragma unroll
        for (int c = 0; c < 2; ++c)
          *(f32x4*)(myreg + ((size_t)(f * 2 + c) * 64 + lane) * 4) = vv[f][c];
      // element (r_local, lcol): frag (f=r>>4, c=lcol>>4), lane q=(r>>2)&3,
      // ln15=lcol&15, comp rr=r&3. Round (c,s): lane -> col=c*16+(lane>>2),
      // r_local = s*16 + (lane&3)*4.
      #pragma unroll
      for (int c = 0; c < 2; ++c) {
        #pragma unroll
        for (int s = 0; s < 4; ++s) {
          f32x4 vr = *(const f32x4*)(myreg +
              ((size_t)(s * 2 + c) * 64 + (lane & 3) * 16 + (lane >> 2)) * 4);
          const int col = nq * 32 + c * 16 + (lane >> 2);
          *(f32x4*)&xoutT[(size_t)col * R_TOTAL + r0 + s * 16 + (lane & 3) * 4] = vr;
        }
      }
    }
  }
}

extern "C" void kernel_launch(void* const* d_in, const int* in_sizes, int n_in,
                              void* d_out, int out_size, void* d_ws, size_t ws_size,
                              hipStream_t stream) {
  const float* in = (const float*)d_in[0];
  const float* W0 = (const float*)d_in[1];
  const float* b0 = (const float*)d_in[2];
  const float* W1 = (const float*)d_in[3];
  const float* b1 = (const float*)d_in[4];
  const float* W2 = (const float*)d_in[5];
  const float* b2 = (const float*)d_in[6];
  float* out = (float*)d_out;

  float* X0T = (float*)d_ws;                         // 32 x 16384   (2 MB)
  float* X1T = X0T + (size_t)32 * R_TOTAL;           // 128 x 16384  (8 MB)
  float* X2T = X1T + (size_t)128 * R_TOTAL;          // 128 x 16384  (8 MB)
  u32* Wt0 = (u32*)(X2T + (size_t)128 * R_TOTAL);    // 32*4*512 u32   (256 KB)
  u32* Wt1 = Wt0 + (size_t)32 * 4 * 512;             // 128*4*512 u32  (1 MB)
  u32* Wt2 = Wt1 + (size_t)128 * 4 * 512;            // 128*4*512 u32  (1 MB)
  // total ws: ~20.3 MB

  prep_all<<<1280, 256, 0, stream>>>(in, X0T, W0, Wt0, W1, Wt1, W2, Wt2);

  layer_mfma<32, true, true><<<256, 512, 0, stream>>>(X0T, X0T, Wt0, b0, X1T, out + 0);
  layer_mfma<128, true, true><<<256, 512, 0, stream>>>(X1T, X0T, Wt1, b1, X2T, out + 128);
  layer_mfma<128, false, false><<<256, 512, 0, stream>>>(X2T, X0T, Wt2, b2, nullptr, out + 256);
}

// Round 15
// 136.376 us; speedup vs baseline: 1.0220x; 1.0057x over previous
//
#include <hip/hip_runtime.h>

// CIN_51539607712 — R17: LDS-free K-loop. R15/R16 nulls prove the ~520cy/wave
// per-h const is not waits/LDS-latency/copies/scheduling — the one component
// never removed is the W round-trip (global_load_lds DMA -> LDS -> ds_read).
// Since R4 each wave consumes a PRIVATE image, the LDS bounce is pure
// overhead: the two ds_read_b128s read a bijective permutation of the
// contiguous 1KB half-image (lane(ln15,q): row*64B + (q^sw)*16B), so the
// same per-lane offsets on the GLOBAL image address are two perfectly
// coalesced global_load_dwordx4 straight into the MFMA B-registers.
// Per-h: 6 vmem (2 B + 4 xl), 8 MFMA, 8 f32x4 fma. No DMA/LDS/lgkm in loop.
// Ledger: group(i)=[B(2),xl(4)] issued at END of iter i-2 (consume-then-
// refill same slot regs, R16-verified order); top-of-iter vmcnt(6) drains
// group(i), leaves group(i+1). Tail: no issue, final vmcnt(0).
// LDS (64KB static) used by epilogue exchange only.
// Numerics = R14 (1-MFMA RNE, absmax 0.125 vs thr 0.4525). Geometry = R4
// champion: grid 256, 512 thr, 8 waves (kh=w&1, nq=w>>1), 64-row blocks.
// out[r,n] = sum_h xl[r,h] * Y_h[r,n],  Y_h[r,n] = sum_m x0[r,m] W[h*32+m,n].

typedef unsigned int u32;
typedef __attribute__((ext_vector_type(8))) short short8;
typedef __attribute__((ext_vector_type(4))) float f32x4;
typedef __attribute__((ext_vector_type(4))) u32 u32x4;

#define R_TOTAL 16384

union PackU { u32 u[4]; short8 s; };
union PackB { u32x4 v; short8 s; };

// pack with round-to-nearest-even (both x0 fragments and W prep)
__device__ __forceinline__ u32 pack_rne(float a, float b) {
  u32 r;
  asm("v_cvt_pk_bf16_f32 %0, %1, %2" : "=v"(r) : "v"(a), "v"(b));
  return r;
}

// ---------------- fused prep kernel ----------------
// blocks 0..127: build X0T[m][b*16+d] = in[b][m][d]  (32 x 16384)
// blocks 128..255 / 256..767 / 768..1279: swizzle W0 / W1 / W2.
__device__ __forceinline__ void build_x0t_body(const float* __restrict__ in,
                                               float* __restrict__ x0t,
                                               int bid, int tid, float* t) {
  const int b0 = bid * 8;
  #pragma unroll
  for (int rep = 0; rep < 4; ++rep) {
    int idx = tid + rep * 256;
    *(float4*)&t[idx * 4] = *(const float4*)&in[(size_t)b0 * 512 + idx * 4];
  }
  __syncthreads();
  #pragma unroll
  for (int rep = 0; rep < 4; ++rep) {
    int idx = tid + rep * 256;     // 0..1023: m(32) x bl(8) x dq(4)
    int m = idx >> 5, rem = idx & 31;
    int bl = rem >> 2, dq = rem & 3;
    *(float4*)&x0t[(size_t)m * R_TOTAL + (b0 + bl) * 16 + dq * 4] =
        *(const float4*)&t[bl * 512 + m * 16 + dq * 4];
  }
}

// Block (t = bid>>2, nq = bid&3). 2 KB image: [nl 0..31][p 0..3] 16B blocks;
// position p holds logical block q = p ^ (nl&3); block q = RNE-packed
// W[t*32+q*8+j][nq*32+nl], j pairs packed (even=lo half, odd=hi half).
__device__ __forceinline__ void swizzle_body(const float* __restrict__ W,
                                             u32* __restrict__ wt,
                                             int bid, int tid, float* wl) {
  const int t = bid >> 2, nq = bid & 3;
  {
    int kk = tid >> 3, c4 = tid & 7;
    float4 v = *(const float4*)&W[(size_t)(t * 32 + kk) * 128 + nq * 32 + c4 * 4];
    wl[kk * 33 + c4 * 4 + 0] = v.x;
    wl[kk * 33 + c4 * 4 + 1] = v.y;
    wl[kk * 33 + c4 * 4 + 2] = v.z;
    wl[kk * 33 + c4 * 4 + 3] = v.w;
  }
  __syncthreads();
  if (tid < 128) {
    int nl = tid >> 2, p = tid & 3;
    int q = p ^ (nl & 3);
    u32 o[4];
    #pragma unroll
    for (int jj = 0; jj < 4; ++jj)
      o[jj] = pack_rne(wl[(q * 8 + 2 * jj + 0) * 33 + nl],
                       wl[(q * 8 + 2 * jj + 1) * 33 + nl]);
    *(u32x4*)(wt + (size_t)(t * 4 + nq) * 512 + nl * 16 + p * 4) =
        u32x4{o[0], o[1], o[2], o[3]};
  }
}

__global__ __launch_bounds__(256) void prep_all(
    const float* __restrict__ in, float* __restrict__ x0t,
    const float* __restrict__ W0, u32* __restrict__ wt0,
    const float* __restrict__ W1, u32* __restrict__ wt1,
    const float* __restrict__ W2, u32* __restrict__ wt2) {
  __shared__ float sh[4096];
  const int b = blockIdx.x, tid = threadIdx.x;
  if (b < 128)      build_x0t_body(in, x0t, b, tid, sh);
  else if (b < 256) swizzle_body(W0, wt0, b - 128, tid, sh);
  else if (b < 768) swizzle_body(W1, wt1, b - 256, tid, sh);
  else              swizzle_body(W2, wt2, b - 768, tid, sh);
}

// s_waitcnt imm (gfx9): vm[3:0]=b3:0, exp=b6:4, lgkm=b11:8, vm[5:4]=b15:14.
// 0x0F76 = vmcnt(6)   0x0F70 = vmcnt(0)
#define SB() __builtin_amdgcn_sched_barrier(0)

// KITER(I): h-tile t0+I, SLOT = I&1. BP = this parity's B-frag regs.
// Order: wait(group I) -> MFMA+fma consume BP/xn[SLOT] -> refill BP/xn[SLOT]
// with group I+2's loads (B first, then xl: 6-op group shape).
#define KITER(I, SLOT, TOPVM, DO_ISSUE, BP)                                    \
  {                                                                            \
    __builtin_amdgcn_s_waitcnt(TOPVM);                                         \
    SB();                                                                      \
    __builtin_amdgcn_s_setprio(1);                                             \
    f32x4 Y0[4], Y1[4];                                                        \
    _Pragma("unroll")                                                          \
    for (int f = 0; f < 4; ++f)                                                \
      Y0[f] = __builtin_amdgcn_mfma_f32_16x16x32_bf16(Ah[f].s, BP[0].s, zero4, 0, 0, 0); \
    _Pragma("unroll")                                                          \
    for (int f = 0; f < 4; ++f)                                                \
      Y1[f] = __builtin_amdgcn_mfma_f32_16x16x32_bf16(Ah[f].s, BP[1].s, zero4, 0, 0, 0); \
    _Pragma("unroll")                                                          \
    for (int f = 0; f < 4; ++f) {                                              \
      acc[f][0] += xn[SLOT][f] * Y0[f];                                        \
      acc[f][1] += xn[SLOT][f] * Y1[f];                                        \
    }                                                                          \
    __builtin_amdgcn_s_setprio(0);                                             \
    SB();                                                                      \
    if (DO_ISSUE) {                                                            \
      const u32* ib = wt + (size_t)((t0 + (I) + 2) * 4 + nq) * 512;            \
      BP[0].v = *(const u32x4*)(ib + boff0);                                   \
      BP[1].v = *(const u32x4*)(ib + boff1);                                   \
      const float* xp = xt + (size_t)(t0 + (I) + 2) * R_TOTAL + r0;            \
      xn[SLOT][0] = *(const f32x4*)(xp + 0 + q * 4);                           \
      xn[SLOT][1] = *(const f32x4*)(xp + 16 + q * 4);                          \
      xn[SLOT][2] = *(const f32x4*)(xp + 32 + q * 4);                          \
      xn[SLOT][3] = *(const f32x4*)(xp + 48 + q * 4);                          \
    }                                                                          \
    SB();                                                                      \
  }

// ---------------- main layer kernel ----------------
template <int NT, bool RELU, bool STORE_X>
__global__ __launch_bounds__(512, 2) void layer_mfma(
    const float* __restrict__ xt,    // NT x R (transposed prev activation)
    const float* __restrict__ x0t,   // 32 x R
    const u32* __restrict__ wt,      // NT*4 quarter images (512 u32 each)
    const float* __restrict__ bias,  // 128
    float* __restrict__ xoutT,       // 128 x R (if STORE_X)
    float* __restrict__ osum)        // d_out + layer offset, stride 384
{
  constexpr int HT = NT / 2;
  static_assert((HT & 1) == 0 && HT >= 4, "pair-loop needs even HT >= 4");
  __shared__ u32 smem[16384];        // 64 KB: epilogue exchange only

  const int tid = threadIdx.x;
  const int w = tid >> 6, lane = tid & 63;
  const int ln15 = lane & 15, q = lane >> 4;
  const int kh = w & 1, nq = w >> 1;
  const int r0 = blockIdx.x * 64;
  const int sw = ln15 & 3;           // matches prep's 4-position XOR layout
  u32* mybuf = smem + w * 2048;

  // per-lane B-frag offsets within a 512-u32 image (loop-invariant)
  const int boff0 = ln15 * 16 + ((q ^ sw) * 4);
  const int boff1 = (16 + ln15) * 16 + ((q ^ sw) * 4);

  // ---- loop-invariant A fragments: RNE-rounded x0 rows (A[i=ln15][k=q*8+j])
  PackU Ah[4];
  #pragma unroll
  for (int f = 0; f < 4; ++f) {
    const int rbase = r0 + f * 16 + ln15;
    float e[8];
    #pragma unroll
    for (int j = 0; j < 8; ++j) e[j] = x0t[(size_t)(q * 8 + j) * R_TOTAL + rbase];
    #pragma unroll
    for (int jj = 0; jj < 4; ++jj)
      Ah[f].u[jj] = pack_rne(e[2 * jj], e[2 * jj + 1]);
  }

  f32x4 acc[4][2];
  #pragma unroll
  for (int f = 0; f < 4; ++f)
    #pragma unroll
    for (int c = 0; c < 2; ++c) acc[f][c] = f32x4{0.f, 0.f, 0.f, 0.f};
  const f32x4 zero4 = {0.f, 0.f, 0.f, 0.f};

  const int t0 = kh * HT;

  // ---- prologue: issue group(0) into (ba, xn[0]), group(1) into (bb, xn[1])
  PackB ba[2], bb[2];
  f32x4 xn[2][4];
  {
    const u32* ib = wt + (size_t)(t0 * 4 + nq) * 512;
    ba[0].v = *(const u32x4*)(ib + boff0);
    ba[1].v = *(const u32x4*)(ib + boff1);
    const float* xp = xt + (size_t)t0 * R_TOTAL + r0;
    xn[0][0] = *(const f32x4*)(xp + 0 + q * 4);
    xn[0][1] = *(const f32x4*)(xp + 16 + q * 4);
    xn[0][2] = *(const f32x4*)(xp + 32 + q * 4);
    xn[0][3] = *(const f32x4*)(xp + 48 + q * 4);
  }
  SB();
  {
    const u32* ib = wt + (size_t)((t0 + 1) * 4 + nq) * 512;
    bb[0].v = *(const u32x4*)(ib + boff0);
    bb[1].v = *(const u32x4*)(ib + boff1);
    const float* xp = xt + (size_t)(t0 + 1) * R_TOTAL + r0;
    xn[1][0] = *(const f32x4*)(xp + 0 + q * 4);
    xn[1][1] = *(const f32x4*)(xp + 16 + q * 4);
    xn[1][2] = *(const f32x4*)(xp + 32 + q * 4);
    xn[1][3] = *(const f32x4*)(xp + 48 + q * 4);
  }
  SB();

  // ---- steady state: top-wait vmcnt(6); refill after consume ----
  for (int i = 0; i < HT - 2; i += 2) {
    KITER(i,     0, 0x0F76, 1, ba);
    KITER(i + 1, 1, 0x0F76, 1, bb);
  }
  // ---- peeled last pair: no issue; final iter drains vmcnt(0) ----
  KITER(HT - 2, 0, 0x0F76, 0, ba);
  KITER(HT - 1, 1, 0x0F70, 0, bb);

  // ---------------- epilogue ----------------
  __syncthreads();
  if (kh == 1) {                    // dump partial acc into own region (8 KB)
    u32* reg = mybuf;
    #pragma unroll
    for (int f = 0; f < 4; ++f)
      #pragma unroll
      for (int c = 0; c < 2; ++c)
        *(f32x4*)(reg + ((size_t)(f * 2 + c) * 64 + lane) * 4) = acc[f][c];
  }
  __syncthreads();
  if (kh == 0) {
    const u32* reg = smem + (w + 1) * 2048;   // partner (kh=1, same nq)
    float bs[2];
    #pragma unroll
    for (int c = 0; c < 2; ++c) bs[c] = bias[nq * 32 + c * 16 + ln15];

    f32x4 vv[4][2];
    #pragma unroll
    for (int f = 0; f < 4; ++f) {
      #pragma unroll
      for (int c = 0; c < 2; ++c) {
        f32x4 part = *(const f32x4*)(reg + ((size_t)(f * 2 + c) * 64 + lane) * 4);
        f32x4 v = acc[f][c] + part;
        v.x += bs[c]; v.y += bs[c]; v.z += bs[c]; v.w += bs[c];
        if (RELU) {
          v.x = fmaxf(v.x, 0.f); v.y = fmaxf(v.y, 0.f);
          v.z = fmaxf(v.z, 0.f); v.w = fmaxf(v.w, 0.f);
        }
        vv[f][c] = v;
        float s = v.x + v.y + v.z + v.w;       // 4 rows of batch (r0>>4)+f
        s += __shfl_xor(s, 16, 64);
        s += __shfl_xor(s, 32, 64);
        if (q == 0)
          osum[(size_t)((r0 >> 4) + f) * 384 + nq * 32 + c * 16 + ln15] = s;
      }
    }

    if (STORE_X) {
      // transpose via own LDS region, then 64B-contiguous stores to XT.
      u32* myreg = mybuf;
      #pragma unroll
      for (int f = 0; f < 4; ++f)
        #pragma unroll
        for (int c = 0; c < 2; ++c)
          *(f32x4*)(myreg + ((size_t)(f * 2 + c) * 64 + lane) * 4) = vv[f][c];
      // element (r_local, lcol): frag (f=r>>4, c=lcol>>4), lane q=(r>>2)&3,
      // ln15=lcol&15, comp rr=r&3. Round (c,s): lane -> col=c*16+(lane>>2),
      // r_local = s*16 + (lane&3)*4.
      #pragma unroll
      for (int c = 0; c < 2; ++c) {
        #pragma unroll
        for (int s = 0; s < 4; ++s) {
          f32x4 vr = *(const f32x4*)(myreg +
              ((size_t)(s * 2 + c) * 64 + (lane & 3) * 16 + (lane >> 2)) * 4);
          const int col = nq * 32 + c * 16 + (lane >> 2);
          *(f32x4*)&xoutT[(size_t)col * R_TOTAL + r0 + s * 16 + (lane & 3) * 4] = vr;
        }
      }
    }
  }
}

extern "C" void kernel_launch(void* const* d_in, const int* in_sizes, int n_in,
                              void* d_out, int out_size, void* d_ws, size_t ws_size,
                              hipStream_t stream) {
  const float* in = (const float*)d_in[0];
  const float* W0 = (const float*)d_in[1];
  const float* b0 = (const float*)d_in[2];
  const float* W1 = (const float*)d_in[3];
  const float* b1 = (const float*)d_in[4];
  const float* W2 = (const float*)d_in[5];
  const float* b2 = (const float*)d_in[6];
  float* out = (float*)d_out;

  float* X0T = (float*)d_ws;                         // 32 x 16384   (2 MB)
  float* X1T = X0T + (size_t)32 * R_TOTAL;           // 128 x 16384  (8 MB)
  float* X2T = X1T + (size_t)128 * R_TOTAL;          // 128 x 16384  (8 MB)
  u32* Wt0 = (u32*)(X2T + (size_t)128 * R_TOTAL);    // 32*4*512 u32   (256 KB)
  u32* Wt1 = Wt0 + (size_t)32 * 4 * 512;             // 128*4*512 u32  (1 MB)
  u32* Wt2 = Wt1 + (size_t)128 * 4 * 512;            // 128*4*512 u32  (1 MB)
  // total ws: ~20.3 MB

  prep_all<<<1280, 256, 0, stream>>>(in, X0T, W0, Wt0, W1, Wt1, W2, Wt2);

  layer_mfma<32, true, true><<<256, 512, 0, stream>>>(X0T, X0T, Wt0, b0, X1T, out + 0);
  layer_mfma<128, true, true><<<256, 512, 0, stream>>>(X1T, X0T, Wt1, b1, X2T, out + 128);
  layer_mfma<128, false, false><<<256, 512, 0, stream>>>(X2T, X0T, Wt2, b2, nullptr, out + 256);
}

// Round 17
// 133.502 us; speedup vs baseline: 1.0440x; 1.0215x over previous
//
#include <hip/hip_runtime.h>

// CIN_51539607712 — R18b: resubmit of R18 (container infra failure, no data).
// R17 with ALL manual scheduling removed.
// R13-R17 ledger: per-wave-h = ~155cy matrix + ~195cy VALU + ~344cy stall
// that survives wait-restructure (R15), LDS-vs-direct (R16/R17), W-volume
// (R13/R14 const flat across 2x line count). The one untested component is
// the hand-ledger itself: rigid vmcnt immediates + 6-8 sched_barrier(0) +
// setprio fence the loop into fixed regions (m141: order-pinning defeats
// the scheduler). The K-loop is now pure-register (R17) -> plain C data
// dependencies are sufficient for correctness; hipcc auto-inserts counted
// vmcnt and can software-pipeline ACROSS h-steps (fill MFMA->fma latency
// bubbles with the next iteration's MFMAs) — forbidden by my fences.
// Same depth-2 consume-then-refill pipeline, expressed as plain C.
// Numerics = R14 (1-MFMA RNE, absmax 0.125 vs thr 0.4525). Geometry = R4
// champion: grid 256, 512 thr, 8 waves (kh=w&1, nq=w>>1), 64-row blocks.
// out[r,n] = sum_h xl[r,h] * Y_h[r,n],  Y_h[r,n] = sum_m x0[r,m] W[h*32+m,n].

typedef unsigned int u32;
typedef __attribute__((ext_vector_type(8))) short short8;
typedef __attribute__((ext_vector_type(4))) float f32x4;
typedef __attribute__((ext_vector_type(4))) u32 u32x4;

#define R_TOTAL 16384

union PackU { u32 u[4]; short8 s; };
union PackB { u32x4 v; short8 s; };

// pack with round-to-nearest-even (both x0 fragments and W prep)
__device__ __forceinline__ u32 pack_rne(float a, float b) {
  u32 r;
  asm("v_cvt_pk_bf16_f32 %0, %1, %2" : "=v"(r) : "v"(a), "v"(b));
  return r;
}

// ---------------- fused prep kernel ----------------
// blocks 0..127: build X0T[m][b*16+d] = in[b][m][d]  (32 x 16384)
// blocks 128..255 / 256..767 / 768..1279: swizzle W0 / W1 / W2.
__device__ __forceinline__ void build_x0t_body(const float* __restrict__ in,
                                               float* __restrict__ x0t,
                                               int bid, int tid, float* t) {
  const int b0 = bid * 8;
  #pragma unroll
  for (int rep = 0; rep < 4; ++rep) {
    int idx = tid + rep * 256;
    *(float4*)&t[idx * 4] = *(const float4*)&in[(size_t)b0 * 512 + idx * 4];
  }
  __syncthreads();
  #pragma unroll
  for (int rep = 0; rep < 4; ++rep) {
    int idx = tid + rep * 256;     // 0..1023: m(32) x bl(8) x dq(4)
    int m = idx >> 5, rem = idx & 31;
    int bl = rem >> 2, dq = rem & 3;
    *(float4*)&x0t[(size_t)m * R_TOTAL + (b0 + bl) * 16 + dq * 4] =
        *(const float4*)&t[bl * 512 + m * 16 + dq * 4];
  }
}

// Block (t = bid>>2, nq = bid&3). 2 KB image: [nl 0..31][p 0..3] 16B blocks;
// position p holds logical block q = p ^ (nl&3); block q = RNE-packed
// W[t*32+q*8+j][nq*32+nl], j pairs packed (even=lo half, odd=hi half).
__device__ __forceinline__ void swizzle_body(const float* __restrict__ W,
                                             u32* __restrict__ wt,
                                             int bid, int tid, float* wl) {
  const int t = bid >> 2, nq = bid & 3;
  {
    int kk = tid >> 3, c4 = tid & 7;
    float4 v = *(const float4*)&W[(size_t)(t * 32 + kk) * 128 + nq * 32 + c4 * 4];
    wl[kk * 33 + c4 * 4 + 0] = v.x;
    wl[kk * 33 + c4 * 4 + 1] = v.y;
    wl[kk * 33 + c4 * 4 + 2] = v.z;
    wl[kk * 33 + c4 * 4 + 3] = v.w;
  }
  __syncthreads();
  if (tid < 128) {
    int nl = tid >> 2, p = tid & 3;
    int q = p ^ (nl & 3);
    u32 o[4];
    #pragma unroll
    for (int jj = 0; jj < 4; ++jj)
      o[jj] = pack_rne(wl[(q * 8 + 2 * jj + 0) * 33 + nl],
                       wl[(q * 8 + 2 * jj + 1) * 33 + nl]);
    *(u32x4*)(wt + (size_t)(t * 4 + nq) * 512 + nl * 16 + p * 4) =
        u32x4{o[0], o[1], o[2], o[3]};
  }
}

__global__ __launch_bounds__(256) void prep_all(
    const float* __restrict__ in, float* __restrict__ x0t,
    const float* __restrict__ W0, u32* __restrict__ wt0,
    const float* __restrict__ W1, u32* __restrict__ wt1,
    const float* __restrict__ W2, u32* __restrict__ wt2) {
  __shared__ float sh[4096];
  const int b = blockIdx.x, tid = threadIdx.x;
  if (b < 128)      build_x0t_body(in, x0t, b, tid, sh);
  else if (b < 256) swizzle_body(W0, wt0, b - 128, tid, sh);
  else if (b < 768) swizzle_body(W1, wt1, b - 256, tid, sh);
  else              swizzle_body(W2, wt2, b - 768, tid, sh);
}

// KITER(I): h-tile t0+I, SLOT = I&1, BP = this parity's B-frag regs.
// Plain C: consume BP/xn[SLOT], then refill with tile I+2's loads.
// No waits / sched_barriers / setprio — data deps carry the hazards;
// the compiler inserts counted vmcnt and pipelines across iterations.
#define KITER(I, SLOT, DO_ISSUE, BP)                                           \
  {                                                                            \
    f32x4 Y0[4], Y1[4];                                                        \
    _Pragma("unroll")                                                          \
    for (int f = 0; f < 4; ++f)                                                \
      Y0[f] = __builtin_amdgcn_mfma_f32_16x16x32_bf16(Ah[f].s, BP[0].s, zero4, 0, 0, 0); \
    _Pragma("unroll")                                                          \
    for (int f = 0; f < 4; ++f)                                                \
      Y1[f] = __builtin_amdgcn_mfma_f32_16x16x32_bf16(Ah[f].s, BP[1].s, zero4, 0, 0, 0); \
    _Pragma("unroll")                                                          \
    for (int f = 0; f < 4; ++f) {                                              \
      acc[f][0] += xn[SLOT][f] * Y0[f];                                        \
      acc[f][1] += xn[SLOT][f] * Y1[f];                                        \
    }                                                                          \
    if (DO_ISSUE) {                                                            \
      const u32* ib = wt + (size_t)((t0 + (I) + 2) * 4 + nq) * 512;            \
      BP[0].v = *(const u32x4*)(ib + boff0);                                   \
      BP[1].v = *(const u32x4*)(ib + boff1);                                   \
      const float* xp = xt + (size_t)(t0 + (I) + 2) * R_TOTAL + r0;            \
      xn[SLOT][0] = *(const f32x4*)(xp + 0 + q * 4);                           \
      xn[SLOT][1] = *(const f32x4*)(xp + 16 + q * 4);                          \
      xn[SLOT][2] = *(const f32x4*)(xp + 32 + q * 4);                          \
      xn[SLOT][3] = *(const f32x4*)(xp + 48 + q * 4);                          \
    }                                                                          \
  }

// ---------------- main layer kernel ----------------
template <int NT, bool RELU, bool STORE_X>
__global__ __launch_bounds__(512, 2) void layer_mfma(
    const float* __restrict__ xt,    // NT x R (transposed prev activation)
    const float* __restrict__ x0t,   // 32 x R
    const u32* __restrict__ wt,      // NT*4 quarter images (512 u32 each)
    const float* __restrict__ bias,  // 128
    float* __restrict__ xoutT,       // 128 x R (if STORE_X)
    float* __restrict__ osum)        // d_out + layer offset, stride 384
{
  constexpr int HT = NT / 2;
  static_assert((HT & 1) == 0 && HT >= 4, "pair-loop needs even HT >= 4");
  __shared__ u32 smem[16384];        // 64 KB: epilogue exchange only

  const int tid = threadIdx.x;
  const int w = tid >> 6, lane = tid & 63;
  const int ln15 = lane & 15, q = lane >> 4;
  const int kh = w & 1, nq = w >> 1;
  const int r0 = blockIdx.x * 64;
  const int sw = ln15 & 3;           // matches prep's 4-position XOR layout
  u32* mybuf = smem + w * 2048;

  // per-lane B-frag offsets within a 512-u32 image (loop-invariant)
  const int boff0 = ln15 * 16 + ((q ^ sw) * 4);
  const int boff1 = (16 + ln15) * 16 + ((q ^ sw) * 4);

  // ---- loop-invariant A fragments: RNE-rounded x0 rows (A[i=ln15][k=q*8+j])
  PackU Ah[4];
  #pragma unroll
  for (int f = 0; f < 4; ++f) {
    const int rbase = r0 + f * 16 + ln15;
    float e[8];
    #pragma unroll
    for (int j = 0; j < 8; ++j) e[j] = x0t[(size_t)(q * 8 + j) * R_TOTAL + rbase];
    #pragma unroll
    for (int jj = 0; jj < 4; ++jj)
      Ah[f].u[jj] = pack_rne(e[2 * jj], e[2 * jj + 1]);
  }

  f32x4 acc[4][2];
  #pragma unroll
  for (int f = 0; f < 4; ++f)
    #pragma unroll
    for (int c = 0; c < 2; ++c) acc[f][c] = f32x4{0.f, 0.f, 0.f, 0.f};
  const f32x4 zero4 = {0.f, 0.f, 0.f, 0.f};

  const int t0 = kh * HT;

  // ---- prologue: load group(0) into (ba, xn[0]), group(1) into (bb, xn[1])
  PackB ba[2], bb[2];
  f32x4 xn[2][4];
  {
    const u32* ib = wt + (size_t)(t0 * 4 + nq) * 512;
    ba[0].v = *(const u32x4*)(ib + boff0);
    ba[1].v = *(const u32x4*)(ib + boff1);
    const float* xp = xt + (size_t)t0 * R_TOTAL + r0;
    xn[0][0] = *(const f32x4*)(xp + 0 + q * 4);
    xn[0][1] = *(const f32x4*)(xp + 16 + q * 4);
    xn[0][2] = *(const f32x4*)(xp + 32 + q * 4);
    xn[0][3] = *(const f32x4*)(xp + 48 + q * 4);
  }
  {
    const u32* ib = wt + (size_t)((t0 + 1) * 4 + nq) * 512;
    bb[0].v = *(const u32x4*)(ib + boff0);
    bb[1].v = *(const u32x4*)(ib + boff1);
    const float* xp = xt + (size_t)(t0 + 1) * R_TOTAL + r0;
    xn[1][0] = *(const f32x4*)(xp + 0 + q * 4);
    xn[1][1] = *(const f32x4*)(xp + 16 + q * 4);
    xn[1][2] = *(const f32x4*)(xp + 32 + q * 4);
    xn[1][3] = *(const f32x4*)(xp + 48 + q * 4);
  }

  // ---- steady state: consume slot, refill with tile i+2 ----
  for (int i = 0; i < HT - 2; i += 2) {
    KITER(i,     0, 1, ba);
    KITER(i + 1, 1, 1, bb);
  }
  // ---- peeled last pair: no refill ----
  KITER(HT - 2, 0, 0, ba);
  KITER(HT - 1, 1, 0, bb);

  // ---------------- epilogue ----------------
  __syncthreads();
  if (kh == 1) {                    // dump partial acc into own region (8 KB)
    u32* reg = mybuf;
    #pragma unroll
    for (int f = 0; f < 4; ++f)
      #pragma unroll
      for (int c = 0; c < 2; ++c)
        *(f32x4*)(reg + ((size_t)(f * 2 + c) * 64 + lane) * 4) = acc[f][c];
  }
  __syncthreads();
  if (kh == 0) {
    const u32* reg = smem + (w + 1) * 2048;   // partner (kh=1, same nq)
    float bs[2];
    #pragma unroll
    for (int c = 0; c < 2; ++c) bs[c] = bias[nq * 32 + c * 16 + ln15];

    f32x4 vv[4][2];
    #pragma unroll
    for (int f = 0; f < 4; ++f) {
      #pragma unroll
      for (int c = 0; c < 2; ++c) {
        f32x4 part = *(const f32x4*)(reg + ((size_t)(f * 2 + c) * 64 + lane) * 4);
        f32x4 v = acc[f][c] + part;
        v.x += bs[c]; v.y += bs[c]; v.z += bs[c]; v.w += bs[c];
        if (RELU) {
          v.x = fmaxf(v.x, 0.f); v.y = fmaxf(v.y, 0.f);
          v.z = fmaxf(v.z, 0.f); v.w = fmaxf(v.w, 0.f);
        }
        vv[f][c] = v;
        float s = v.x + v.y + v.z + v.w;       // 4 rows of batch (r0>>4)+f
        s += __shfl_xor(s, 16, 64);
        s += __shfl_xor(s, 32, 64);
        if (q == 0)
          osum[(size_t)((r0 >> 4) + f) * 384 + nq * 32 + c * 16 + ln15] = s;
      }
    }

    if (STORE_X) {
      // transpose via own LDS region, then 64B-contiguous stores to XT.
      u32* myreg = mybuf;
      #pragma unroll
      for (int f = 0; f < 4; ++f)
        #pragma unroll
        for (int c = 0; c < 2; ++c)
          *(f32x4*)(myreg + ((size_t)(f * 2 + c) * 64 + lane) * 4) = vv[f][c];
      // element (r_local, lcol): frag (f=r>>4, c=lcol>>4), lane q=(r>>2)&3,
      // ln15=lcol&15, comp rr=r&3. Round (c,s): lane -> col=c*16+(lane>>2),
      // r_local = s*16 + (lane&3)*4.
      #pragma unroll
      for (int c = 0; c < 2; ++c) {
        #pragma unroll
        for (int s = 0; s < 4; ++s) {
          f32x4 vr = *(const f32x4*)(myreg +
              ((size_t)(s * 2 + c) * 64 + (lane & 3) * 16 + (lane >> 2)) * 4);
          const int col = nq * 32 + c * 16 + (lane >> 2);
          *(f32x4*)&xoutT[(size_t)col * R_TOTAL + r0 + s * 16 + (lane & 3) * 4] = vr;
        }
      }
    }
  }
}

extern "C" void kernel_launch(void* const* d_in, const int* in_sizes, int n_in,
                              void* d_out, int out_size, void* d_ws, size_t ws_size,
                              hipStream_t stream) {
  const float* in = (const float*)d_in[0];
  const float* W0 = (const float*)d_in[1];
  const float* b0 = (const float*)d_in[2];
  const float* W1 = (const float*)d_in[3];
  const float* b1 = (const float*)d_in[4];
  const float* W2 = (const float*)d_in[5];
  const float* b2 = (const float*)d_in[6];
  float* out = (float*)d_out;

  float* X0T = (float*)d_ws;                         // 32 x 16384   (2 MB)
  float* X1T = X0T + (size_t)32 * R_TOTAL;           // 128 x 16384  (8 MB)
  float* X2T = X1T + (size_t)128 * R_TOTAL;          // 128 x 16384  (8 MB)
  u32* Wt0 = (u32*)(X2T + (size_t)128 * R_TOTAL);    // 32*4*512 u32   (256 KB)
  u32* Wt1 = Wt0 + (size_t)32 * 4 * 512;             // 128*4*512 u32  (1 MB)
  u32* Wt2 = Wt1 + (size_t)128 * 4 * 512;            // 128*4*512 u32  (1 MB)
  // total ws: ~20.3 MB

  prep_all<<<1280, 256, 0, stream>>>(in, X0T, W0, Wt0, W1, Wt1, W2, Wt2);

  layer_mfma<32, true, true><<<256, 512, 0, stream>>>(X0T, X0T, Wt0, b0, X1T, out + 0);
  layer_mfma<128, true, true><<<256, 512, 0, stream>>>(X1T, X0T, Wt1, b1, X2T, out + 128);
  layer_mfma<128, false, false><<<256, 512, 0, stream>>>(X2T, X0T, Wt2, b2, nullptr, out + 256);
}